// Round 6
// baseline (514.312 us; speedup 1.0000x reference)
//
#include <hip/hip_runtime.h>
#include <cstdint>
#include <cstddef>

// x: [512][64][1024], conv1: K=32 S=16 -> T=63, Cout=256
// z1 stored PADDED: [n][t'][c], t' = t+1, rows 0, 64, 65 are zero (halo).
// fp16 2-limb: v ~= hi + lo*(1/2048), hi=fp16(v), lo=fp16((v-hi)*2048)

typedef _Float16 half8 __attribute__((ext_vector_type(8)));
typedef float floatx4 __attribute__((ext_vector_type(4)));

__device__ __forceinline__ void split_f32(float v, _Float16& hi, _Float16& lo) {
    _Float16 h = (_Float16)v;
    hi = h;
    lo = (_Float16)((v - (float)h) * 2048.0f);
}

// global -> LDS direct DMA, 16B per lane (wave-uniform LDS base + lane*16)
typedef const __attribute__((address_space(1))) unsigned int* gas_ptr;
typedef __attribute__((address_space(3))) unsigned int* las_ptr;
__device__ __forceinline__ void lds_dma16(const void* g, void* l) {
    __builtin_amdgcn_global_load_lds((gas_ptr)g, (las_ptr)l, 16, 0, 0);
}

// ---------------------------------------------------------------------------
// K0: prep — BN fold, fp16 limb splits, z1p halo-row zeroing (rows 0,64,65)
// ---------------------------------------------------------------------------
__global__ __launch_bounds__(256) void prep_kernel(
    const float* __restrict__ c1w, const float* __restrict__ c1b,
    const float* __restrict__ g1,  const float* __restrict__ b1,
    const float* __restrict__ m1,  const float* __restrict__ v1,
    const float* __restrict__ c2w, const float* __restrict__ c2b,
    const float* __restrict__ g2,  const float* __restrict__ b2,
    const float* __restrict__ m2,  const float* __restrict__ v2,
    const float* __restrict__ w1,
    _Float16* __restrict__ w1h, _Float16* __restrict__ w1l,
    _Float16* __restrict__ w2h, _Float16* __restrict__ w2l,
    _Float16* __restrict__ wdh, _Float16* __restrict__ wdl,
    _Float16* __restrict__ z1ph, _Float16* __restrict__ z1pl,
    float* __restrict__ ab1, float* __restrict__ ab2)
{
    const int id = blockIdx.x * 256 + threadIdx.x;   // 65536 total
    if (id < 256) {
        float a1 = g1[id] / sqrtf(v1[id] + 1e-5f);
        ab1[id]       = a1;
        ab1[256 + id] = (c1b[id] - m1[id]) * a1 + b1[id];
        float a2 = g2[id] / sqrtf(v2[id] + 1e-5f);
        ab2[id]       = a2;
        ab2[256 + id] = (c2b[id] - m2[id]) * a2 + b2[id];
    }
    // zero z1p halo rows {0,64,65} for all n: 512 n * 3 rows * 64 short4 = 98304
    {
        short4 zz = {0, 0, 0, 0};
        for (int idx = id; idx < 98304; idx += 65536) {
            const int n = idx / 192;
            const int r = idx - n * 192;
            const int rs = r >> 6;                       // 0,1,2
            const int row = (rs == 0) ? 0 : (63 + rs);   // 0,64,65
            const int c0 = (r & 63) * 4;
            const size_t off = ((size_t)n * 66 + row) * 256 + c0;
            *(short4*)&z1ph[off] = zz;
            *(short4*)&z1pl[off] = zz;
        }
    }
    // dense1 weights: w1[o][c] row-major already == B-row layout [o][k=c]
    split_f32(w1[id], wdh[id], wdl[id]);
    // conv1_w limbs: [o][2048] direct layout
    for (int idx = id; idx < 256 * 2048; idx += 65536)
        split_f32(c1w[idx], w1h[idx], w1l[idx]);
    // conv2_w limbs transposed to [o][dt*256+c]
    for (int idx = id; idx < 256 * 768; idx += 65536) {
        const int o  = idx / 768;
        const int r  = idx - o * 768;
        const int dt = r >> 8;
        const int c  = r & 255;
        split_f32(c2w[o * 768 + c * 3 + dt], w2h[idx], w2l[idx]);
    }
}

// ---------------------------------------------------------------------------
// K1: conv1 + bn1, fp16 2-limb MFMA GEMM. M=32256, K=2048 (c*32+k), N=256.
// Proven 157-µs structure; epilogue writes PADDED z1p (stride 66) rows t+1.
// ---------------------------------------------------------------------------
__global__ __launch_bounds__(256, 2) void conv1_mfma(
    const float* __restrict__ x,
    const _Float16* __restrict__ w1h, const _Float16* __restrict__ w1l,
    const float* __restrict__ ab,
    _Float16* __restrict__ z1ph, _Float16* __restrict__ z1pl)
{
    __shared__ _Float16 Ah[4][128][8];   // [k-quad][m][8] fragment-major
    __shared__ _Float16 Al[4][128][8];
    __shared__ _Float16 Bh[4][128][8];
    __shared__ _Float16 Bl[4][128][8];

    const int tid = threadIdx.x;
    const int bm = blockIdx.x, bn = blockIdx.y;
    const int lr = tid & 127;
    const int h  = tid >> 7;

    const int am = bm * 128 + lr;
    const int an = am / 63, at = am - an * 63;
    const float*    arow  = x   + (size_t)an * 65536 + at * 16 + h * 16;
    const _Float16* bhrow = w1h + (size_t)(bn * 128 + lr) * 2048 + h * 16;
    const _Float16* blrow = w1l + (size_t)(bn * 128 + lr) * 2048 + h * 16;

    const int lane = tid & 63;
    const int wv   = tid >> 6;
    const int mw   = wv & 1, nw = wv >> 1;
    const int quad = lane >> 4;
    const int l15  = lane & 15;

    floatx4 accA[4][4] = {};
    floatx4 accB[4][4] = {};

    for (int it = 0; it < 64; ++it) {
        const float* ap = arow + it * 1024;
        float va[16];
        *(float4*)&va[0]  = *(const float4*)(ap);
        *(float4*)&va[4]  = *(const float4*)(ap + 4);
        *(float4*)&va[8]  = *(const float4*)(ap + 8);
        *(float4*)&va[12] = *(const float4*)(ap + 12);
        int4 bh0 = *(const int4*)(bhrow + it * 32);
        int4 bh1 = *(const int4*)(bhrow + it * 32 + 8);
        int4 bl0 = *(const int4*)(blrow + it * 32);
        int4 bl1 = *(const int4*)(blrow + it * 32 + 8);

        union U { _Float16 hf[8]; int4 v; };
        U c0h, c0l, c1h, c1l;
#pragma unroll
        for (int j = 0; j < 8; ++j) split_f32(va[j],     c0h.hf[j], c0l.hf[j]);
#pragma unroll
        for (int j = 0; j < 8; ++j) split_f32(va[8 + j], c1h.hf[j], c1l.hf[j]);

        __syncthreads();
        *(int4*)&Ah[2*h  ][lr][0] = c0h.v;
        *(int4*)&Ah[2*h+1][lr][0] = c1h.v;
        *(int4*)&Al[2*h  ][lr][0] = c0l.v;
        *(int4*)&Al[2*h+1][lr][0] = c1l.v;
        *(int4*)&Bh[2*h  ][lr][0] = bh0;
        *(int4*)&Bh[2*h+1][lr][0] = bh1;
        *(int4*)&Bl[2*h  ][lr][0] = bl0;
        *(int4*)&Bl[2*h+1][lr][0] = bl1;
        __syncthreads();

        half8 fah[4], fal[4], fbh[4], fbl[4];
#pragma unroll
        for (int t = 0; t < 4; ++t) {
            fah[t] = *(const half8*)&Ah[quad][mw*64 + t*16 + l15][0];
            fal[t] = *(const half8*)&Al[quad][mw*64 + t*16 + l15][0];
            fbh[t] = *(const half8*)&Bh[quad][nw*64 + t*16 + l15][0];
            fbl[t] = *(const half8*)&Bl[quad][nw*64 + t*16 + l15][0];
        }
#pragma unroll
        for (int ti = 0; ti < 4; ++ti)
#pragma unroll
            for (int tj = 0; tj < 4; ++tj) {
                accA[ti][tj] = __builtin_amdgcn_mfma_f32_16x16x32_f16(fah[ti], fbh[tj], accA[ti][tj], 0, 0, 0);
                accB[ti][tj] = __builtin_amdgcn_mfma_f32_16x16x32_f16(fah[ti], fbl[tj], accB[ti][tj], 0, 0, 0);
                accB[ti][tj] = __builtin_amdgcn_mfma_f32_16x16x32_f16(fal[ti], fbh[tj], accB[ti][tj], 0, 0, 0);
            }
    }

#pragma unroll
    for (int tj = 0; tj < 4; ++tj) {
        const int o = bn*128 + nw*64 + tj*16 + l15;
        const float alpha = ab[o], beta = ab[256 + o];
#pragma unroll
        for (int ti = 0; ti < 4; ++ti) {
            const int m0 = bm*128 + mw*64 + ti*16 + quad*4;
#pragma unroll
            for (int r = 0; r < 4; ++r) {
                float c = accA[ti][tj][r] + accB[ti][tj][r] * (1.0f/2048.0f);
                float z = c * alpha + beta;
                _Float16 zh, zl;
                split_f32(z, zh, zl);
                const int m  = m0 + r;
                const int a2 = m / 63;
                const int t2 = m - a2 * 63;
                const size_t off = ((size_t)a2 * 66 + t2 + 1) * 256 + o;  // padded row t+1
                z1ph[off] = zh;
                z1pl[off] = zl;
            }
        }
    }
}

// ---------------------------------------------------------------------------
// K2: FUSED TAIL — conv2+bn2 -> cuba1 -> dense1 -> cuba2 -> dense2 -> cuba3.
// One block per batch item n. BM=64 (t rows, t=63 pad), BN=256 (wave wv owns
// o = wv*64..+63). Scans run IN-REGISTER on the MFMA accumulator via
// __shfl broadcast (t = ti*16 + quad*4 + r lives in lane l15+16*quad).
// Spikes held in a swizzled 32 KB LDS tile; masks in LDS; nothing but the
// final out[] touches HBM after z1p/weights are read.
// ---------------------------------------------------------------------------
__global__ __launch_bounds__(256, 2) void fused_tail(
    const _Float16* __restrict__ z1ph, const _Float16* __restrict__ z1pl,
    const _Float16* __restrict__ w2h, const _Float16* __restrict__ w2l,
    const _Float16* __restrict__ wdh, const _Float16* __restrict__ wdl,
    const float* __restrict__ ab, const float* __restrict__ w2f,
    float* __restrict__ out)
{
    __shared__ _Float16 BSTh[4][256][8];   // 16 KB  B staging hi (phase A & B)
    __shared__ _Float16 BSTl[4][256][8];   // 16 KB  B staging lo
    __shared__ _Float16 ASTh[4][64][8];    //  4 KB  A staging hi (phase A)
    __shared__ _Float16 ASTl[4][64][8];    //  4 KB  A staging lo
    __shared__ _Float16 S1T[64 * 256];     // 32 KB  spike tile (XOR-swizzled)
    __shared__ unsigned long long M2[256]; //  2 KB  cuba2 spike masks
    __shared__ float Y[126];

    const int tid  = threadIdx.x;
    const int n    = blockIdx.x;
    const int lane = tid & 63;
    const int wv   = tid >> 6;
    const int quad = lane >> 4;
    const int l15  = lane & 15;
    const int arow = tid & 63;             // A-staging row (m = t)
    const int kq   = tid >> 6;             // A-staging k-quad

    const _Float16* z1h_n = z1ph + (size_t)n * 16896;   // 66*256
    const _Float16* z1l_n = z1pl + (size_t)n * 16896;
    const _Float16* w2h_t = w2h + (size_t)tid * 768;    // B row o = tid
    const _Float16* w2l_t = w2l + (size_t)tid * 768;
    const _Float16* wdh_t = wdh + (size_t)tid * 256;
    const _Float16* wdl_t = wdl + (size_t)tid * 256;

    floatx4 accA[4][4] = {};
    floatx4 accB[4][4] = {};

    // zero the pad row of the spike tile (read by dense1's m=63, discarded)
    S1T[63 * 256 + tid] = (_Float16)0.0f;

    // ================= Phase A: conv2 GEMM, K=768 (24 x BK=32) =============
    for (int it = 0; it < 24; ++it) {
        const int dt = it >> 3;
        const int c0 = (it & 7) * 32;
        __syncthreads();                   // previous tile consumed
        // A reg-stage: 64 rows x 32 k, 2 limbs
        int4 vh = *(const int4*)(z1h_n + (arow + dt) * 256 + c0 + kq * 8);
        int4 vl = *(const int4*)(z1l_n + (arow + dt) * 256 + c0 + kq * 8);
        // B DMA: [kq][o=tid][8], linear in lane
#pragma unroll
        for (int q = 0; q < 4; ++q) {
            lds_dma16(w2h_t + it * 32 + q * 8, &BSTh[q][tid][0]);
            lds_dma16(w2l_t + it * 32 + q * 8, &BSTl[q][tid][0]);
        }
        *(int4*)&ASTh[kq][arow][0] = vh;
        *(int4*)&ASTl[kq][arow][0] = vl;
        __syncthreads();                   // drains DMA + LDS writes

        half8 fah[4], fal[4], fbh[4], fbl[4];
#pragma unroll
        for (int t = 0; t < 4; ++t) {
            fah[t] = *(const half8*)&ASTh[quad][t*16 + l15][0];
            fal[t] = *(const half8*)&ASTl[quad][t*16 + l15][0];
            fbh[t] = *(const half8*)&BSTh[quad][wv*64 + t*16 + l15][0];
            fbl[t] = *(const half8*)&BSTl[quad][wv*64 + t*16 + l15][0];
        }
#pragma unroll
        for (int ti = 0; ti < 4; ++ti)
#pragma unroll
            for (int tj = 0; tj < 4; ++tj) {
                accA[ti][tj] = __builtin_amdgcn_mfma_f32_16x16x32_f16(fah[ti], fbh[tj], accA[ti][tj], 0, 0, 0);
                accB[ti][tj] = __builtin_amdgcn_mfma_f32_16x16x32_f16(fah[ti], fbl[tj], accB[ti][tj], 0, 0, 0);
                accB[ti][tj] = __builtin_amdgcn_mfma_f32_16x16x32_f16(fal[ti], fbh[tj], accB[ti][tj], 0, 0, 0);
            }
    }

    // ============== cuba1: in-register scan (shfl broadcast) ===============
    {
        float al4[4], be4[4], cur[4] = {0,0,0,0}, vol[4] = {0,0,0,0};
#pragma unroll
        for (int tj = 0; tj < 4; ++tj) {
            const int o = wv*64 + tj*16 + l15;
            al4[tj] = ab[o]; be4[tj] = ab[256 + o];
        }
#pragma unroll
        for (int seg = 0; seg < 16; ++seg) {
            const int sq = seg & 3, ti = seg >> 2;
#pragma unroll
            for (int r = 0; r < 4; ++r) {
                const int t = seg * 4 + r;      // = ti*16 + sq*4 + r
                if (t < 63) {
#pragma unroll
                    for (int tj = 0; tj < 4; ++tj) {
                        float zown = accA[ti][tj][r] + accB[ti][tj][r] * (1.0f/2048.0f);
                        float zb = __shfl(zown, l15 + (sq << 4));
                        float xv = zb * al4[tj] + be4[tj];
                        cur[tj] = 0.1f * cur[tj] + xv;
                        vol[tj] = 0.1f * vol[tj] + cur[tj];
                        bool sp = (vol[tj] - 0.3f) >= 0.f;
                        if (quad == 0) {
                            const int o = wv*64 + tj*16 + l15;
                            S1T[t * 256 + (o ^ ((t & 7) << 3))] =
                                sp ? (_Float16)1.0f : (_Float16)0.0f;
                        }
                        if (sp) vol[tj] = 0.f;
                    }
                }
            }
        }
    }

    // ================ Phase B: dense1 GEMM, K=256 (8 x BK=32) ==============
    {
        const floatx4 zv = {0.f, 0.f, 0.f, 0.f};
#pragma unroll
        for (int ti = 0; ti < 4; ++ti)
#pragma unroll
            for (int tj = 0; tj < 4; ++tj) { accA[ti][tj] = zv; accB[ti][tj] = zv; }
    }
    for (int it = 0; it < 8; ++it) {
        const int c0 = it * 32;
        __syncthreads();                   // covers S1T writes (it=0) / BST reads
#pragma unroll
        for (int q = 0; q < 4; ++q) {
            lds_dma16(wdh_t + c0 + q * 8, &BSTh[q][tid][0]);
            lds_dma16(wdl_t + c0 + q * 8, &BSTl[q][tid][0]);
        }
        __syncthreads();

        half8 fa[4], fbh[4], fbl[4];
#pragma unroll
        for (int t = 0; t < 4; ++t) {
            const int row = t*16 + l15;
            fa[t] = *(const half8*)&S1T[row * 256 + ((c0 + quad*8) ^ ((row & 7) << 3))];
            fbh[t] = *(const half8*)&BSTh[quad][wv*64 + t*16 + l15][0];
            fbl[t] = *(const half8*)&BSTl[quad][wv*64 + t*16 + l15][0];
        }
#pragma unroll
        for (int ti = 0; ti < 4; ++ti)
#pragma unroll
            for (int tj = 0; tj < 4; ++tj) {
                accA[ti][tj] = __builtin_amdgcn_mfma_f32_16x16x32_f16(fa[ti], fbh[tj], accA[ti][tj], 0, 0, 0);
                accB[ti][tj] = __builtin_amdgcn_mfma_f32_16x16x32_f16(fa[ti], fbl[tj], accB[ti][tj], 0, 0, 0);
            }
    }

    // ============== cuba2: in-register scan -> 63-bit masks ================
    {
        unsigned long long mk[4] = {0ull, 0ull, 0ull, 0ull};
        float v4[4] = {0.f, 0.f, 0.f, 0.f};
#pragma unroll
        for (int seg = 0; seg < 16; ++seg) {
            const int sq = seg & 3, ti = seg >> 2;
#pragma unroll
            for (int r = 0; r < 4; ++r) {
                const int t = seg * 4 + r;
                if (t < 63) {
#pragma unroll
                    for (int tj = 0; tj < 4; ++tj) {
                        float yown = accA[ti][tj][r] + accB[ti][tj][r] * (1.0f/2048.0f);
                        float yb = __shfl(yown, l15 + (sq << 4));
                        v4[tj] = 0.9f * v4[tj] + yb;
                        if ((v4[tj] - 0.1f) >= 0.f) { mk[tj] |= (1ull << t); v4[tj] = 0.f; }
                    }
                }
            }
        }
        if (quad == 0) {
#pragma unroll
            for (int tj = 0; tj < 4; ++tj)
                M2[wv*64 + tj*16 + l15] = mk[tj];
        }
    }
    __syncthreads();

    // ================== Phase C: dense2 + cuba3 -> out =====================
    if (tid < 126) {
        const int cls = tid / 63;
        const int t   = tid - cls * 63;
        const float* wrow = w2f + cls * 256;
        float acc = 0.f;
#pragma unroll 4
        for (int o = 0; o < 256; ++o)
            acc += ((M2[o] >> t) & 1ull) ? wrow[o] : 0.f;
        Y[cls * 63 + t] = acc;
    }
    __syncthreads();
    if (tid < 2) {
        float v = 0.f;
        float* orow = out + (size_t)n * 126 + tid * 63;
        for (int t = 0; t < 63; ++t) {
            v = 0.9f * v + Y[tid * 63 + t];
            float u = v - 0.1f;
            float s = (u >= 0.f) ? 1.f : 0.f;
            orow[t] = s;
            v = (u >= 0.f) ? 0.f : v;
        }
    }
}

// ---------------------------------------------------------------------------
extern "C" void kernel_launch(void* const* d_in, const int* in_sizes, int n_in,
                              void* d_out, int out_size, void* d_ws, size_t ws_size,
                              hipStream_t stream)
{
    const float* x    = (const float*)d_in[0];
    const float* c1w  = (const float*)d_in[1];
    const float* c1b  = (const float*)d_in[2];
    const float* g1   = (const float*)d_in[3];
    const float* b1   = (const float*)d_in[4];
    const float* m1   = (const float*)d_in[5];
    const float* v1   = (const float*)d_in[6];
    const float* c2w  = (const float*)d_in[7];
    const float* c2b  = (const float*)d_in[8];
    const float* g2   = (const float*)d_in[9];
    const float* b2   = (const float*)d_in[10];
    const float* m2   = (const float*)d_in[11];
    const float* v2   = (const float*)d_in[12];
    const float* w1   = (const float*)d_in[13];
    const float* w2   = (const float*)d_in[14];
    float* out = (float*)d_out;

    float* ws = (float*)d_ws;
    // layout (float units):
    //   [0,        4325376)   z1ph  (padded [512][66][256] fp16)
    //   [4325376,  8650752)   z1pl
    //   [8650752,  ...)       weight limbs + ab
    _Float16* z1ph = (_Float16*)ws;
    _Float16* z1pl = (_Float16*)(ws + 4325376);
    float*    wsp  = ws + 8650752;
    _Float16* w1h = (_Float16*)wsp;                                 // 262,144 f
    _Float16* w1l = (_Float16*)(wsp + 262144);                      // 262,144 f
    _Float16* w2h = (_Float16*)(wsp + 2*262144);                    //  98,304 f
    _Float16* w2l = (_Float16*)(wsp + 2*262144 + 98304);            //  98,304 f
    _Float16* wdh = (_Float16*)(wsp + 2*262144 + 2*98304);          //  32,768 f
    _Float16* wdl = (_Float16*)(wsp + 2*262144 + 2*98304 + 32768);  //  32,768 f
    float*    ab1 = wsp + 2*262144 + 2*98304 + 2*32768;
    float*    ab2 = ab1 + 512;

    prep_kernel<<<256, 256, 0, stream>>>(c1w, c1b, g1, b1, m1, v1,
                                         c2w, c2b, g2, b2, m2, v2,
                                         w1, w1h, w1l, w2h, w2l, wdh, wdl,
                                         z1ph, z1pl, ab1, ab2);
    conv1_mfma<<<dim3(252, 2), 256, 0, stream>>>(x, w1h, w1l, ab1, z1ph, z1pl);
    fused_tail<<<512, 256, 0, stream>>>(z1ph, z1pl, w2h, w2l, wdh, wdl,
                                        ab2, w2, out);
}

// Round 7
// 429.750 us; speedup vs baseline: 1.1968x; 1.1968x over previous
//
#include <hip/hip_runtime.h>
#include <cstdint>
#include <cstddef>

// x: [512][64][1024], conv1: K=32 S=16 -> T=63, Cout=256
// z1 stored PADDED: [n][t'][c], t' = t+1, rows 0, 64, 65 are zero (halo).
// fp16 2-limb: v ~= hi + lo*(1/2048), hi=fp16(v), lo=fp16((v-hi)*2048)

typedef _Float16 half8 __attribute__((ext_vector_type(8)));
typedef float floatx4 __attribute__((ext_vector_type(4)));

__device__ __forceinline__ void split_f32(float v, _Float16& hi, _Float16& lo) {
    _Float16 h = (_Float16)v;
    hi = h;
    lo = (_Float16)((v - (float)h) * 2048.0f);
}

// global -> LDS direct DMA, 16B per lane (wave-uniform LDS base + lane*16)
typedef const __attribute__((address_space(1))) unsigned int* gas_ptr;
typedef __attribute__((address_space(3))) unsigned int* las_ptr;
__device__ __forceinline__ void lds_dma16(const void* g, void* l) {
    __builtin_amdgcn_global_load_lds((gas_ptr)g, (las_ptr)l, 16, 0, 0);
}

// 4-wide split: float4 -> two short4 (bit patterns of fp16 limbs)
union H4 { _Float16 hf[4]; short4 s; };
__device__ __forceinline__ void split4(const float4 v, short4& hi4, short4& lo4) {
    H4 hh, ll;
    split_f32(v.x, hh.hf[0], ll.hf[0]);
    split_f32(v.y, hh.hf[1], ll.hf[1]);
    split_f32(v.z, hh.hf[2], ll.hf[2]);
    split_f32(v.w, hh.hf[3], ll.hf[3]);
    hi4 = hh.s; lo4 = ll.s;
}

// ---------------------------------------------------------------------------
// K0: prep — BN fold, fp16 limb splits, z1p halo zeroing.
// FULLY PARALLEL: 1024 blocks x 256 threads, range-partitioned, vectorized.
// (old version: 256 blocks, scalar strided loops — suspected ~134 us sink)
// ---------------------------------------------------------------------------
__global__ __launch_bounds__(256) void prep_kernel(
    const float* __restrict__ c1w, const float* __restrict__ c1b,
    const float* __restrict__ g1,  const float* __restrict__ b1,
    const float* __restrict__ m1,  const float* __restrict__ v1,
    const float* __restrict__ c2w, const float* __restrict__ c2b,
    const float* __restrict__ g2,  const float* __restrict__ b2,
    const float* __restrict__ m2,  const float* __restrict__ v2,
    const float* __restrict__ w1,
    _Float16* __restrict__ w1h, _Float16* __restrict__ w1l,
    _Float16* __restrict__ w2h, _Float16* __restrict__ w2l,
    _Float16* __restrict__ wdh, _Float16* __restrict__ wdl,
    _Float16* __restrict__ z1ph, _Float16* __restrict__ z1pl,
    float* __restrict__ ab1, float* __restrict__ ab2)
{
    const int id = blockIdx.x * 256 + threadIdx.x;   // 262144 total

    if (id < 256) {                                  // BN fold
        float a1 = g1[id] / sqrtf(v1[id] + 1e-5f);
        ab1[id]       = a1;
        ab1[256 + id] = (c1b[id] - m1[id]) * a1 + b1[id];
        float a2 = g2[id] / sqrtf(v2[id] + 1e-5f);
        ab2[id]       = a2;
        ab2[256 + id] = (c2b[id] - m2[id]) * a2 + b2[id];
    }

    if (id < 131072) {                               // c1w: 524288 f, float4/thread
        float4 v = *(const float4*)(c1w + (size_t)id * 4);
        short4 h4, l4;
        split4(v, h4, l4);
        *(short4*)&w1h[(size_t)id * 4] = h4;
        *(short4*)&w1l[(size_t)id * 4] = l4;
    } else if (id < 147456) {                        // w1 dense: 65536 f
        const int i4 = id - 131072;
        float4 v = *(const float4*)(w1 + (size_t)i4 * 4);
        short4 h4, l4;
        split4(v, h4, l4);
        *(short4*)&wdh[(size_t)i4 * 4] = h4;
        *(short4*)&wdl[(size_t)i4 * 4] = l4;
    } else if (id < 196608) {                        // c2w transpose: 196608 f
        const int i4  = id - 147456;                 // [0, 49152)
        const int idx = i4 * 4;                      // dest base; same o,dt for all 4
        const int o   = idx / 768;
        const int r   = idx - o * 768;
        const int dt  = r >> 8;
        const int c0  = r & 255;
        const float* src = c2w + (size_t)o * 768 + dt;
        float4 v;
        v.x = src[(c0    ) * 3];
        v.y = src[(c0 + 1) * 3];
        v.z = src[(c0 + 2) * 3];
        v.w = src[(c0 + 3) * 3];
        short4 h4, l4;
        split4(v, h4, l4);
        *(short4*)&w2h[idx] = h4;
        *(short4*)&w2l[idx] = l4;
    } else {                                         // z1p halo rows {0,64,65}
        const short4 zz = {0, 0, 0, 0};
        for (int s = id - 196608; s < 98304; s += 65536) {
            const int n   = s / 192;
            const int r   = s - n * 192;
            const int rs  = r >> 6;                  // 0,1,2
            const int row = (rs == 0) ? 0 : (63 + rs);
            const int c0  = (r & 63) * 4;
            const size_t off = ((size_t)n * 66 + row) * 256 + c0;
            *(short4*)&z1ph[off] = zz;
            *(short4*)&z1pl[off] = zz;
        }
    }
}

// ---------------------------------------------------------------------------
// K1: conv1 + bn1, fp16 2-limb MFMA GEMM. M=32256, K=2048 (c*32+k), N=256.
// Proven 157-us structure; epilogue writes PADDED z1p (stride 66) rows t+1.
// ---------------------------------------------------------------------------
__global__ __launch_bounds__(256, 2) void conv1_mfma(
    const float* __restrict__ x,
    const _Float16* __restrict__ w1h, const _Float16* __restrict__ w1l,
    const float* __restrict__ ab,
    _Float16* __restrict__ z1ph, _Float16* __restrict__ z1pl)
{
    __shared__ _Float16 Ah[4][128][8];   // [k-quad][m][8] fragment-major
    __shared__ _Float16 Al[4][128][8];
    __shared__ _Float16 Bh[4][128][8];
    __shared__ _Float16 Bl[4][128][8];

    const int tid = threadIdx.x;
    const int bm = blockIdx.x, bn = blockIdx.y;
    const int lr = tid & 127;
    const int h  = tid >> 7;

    const int am = bm * 128 + lr;
    const int an = am / 63, at = am - an * 63;
    const float*    arow  = x   + (size_t)an * 65536 + at * 16 + h * 16;
    const _Float16* bhrow = w1h + (size_t)(bn * 128 + lr) * 2048 + h * 16;
    const _Float16* blrow = w1l + (size_t)(bn * 128 + lr) * 2048 + h * 16;

    const int lane = tid & 63;
    const int wv   = tid >> 6;
    const int mw   = wv & 1, nw = wv >> 1;
    const int quad = lane >> 4;
    const int l15  = lane & 15;

    floatx4 accA[4][4] = {};
    floatx4 accB[4][4] = {};

    for (int it = 0; it < 64; ++it) {
        const float* ap = arow + it * 1024;
        float va[16];
        *(float4*)&va[0]  = *(const float4*)(ap);
        *(float4*)&va[4]  = *(const float4*)(ap + 4);
        *(float4*)&va[8]  = *(const float4*)(ap + 8);
        *(float4*)&va[12] = *(const float4*)(ap + 12);
        int4 bh0 = *(const int4*)(bhrow + it * 32);
        int4 bh1 = *(const int4*)(bhrow + it * 32 + 8);
        int4 bl0 = *(const int4*)(blrow + it * 32);
        int4 bl1 = *(const int4*)(blrow + it * 32 + 8);

        union U { _Float16 hf[8]; int4 v; };
        U c0h, c0l, c1h, c1l;
#pragma unroll
        for (int j = 0; j < 8; ++j) split_f32(va[j],     c0h.hf[j], c0l.hf[j]);
#pragma unroll
        for (int j = 0; j < 8; ++j) split_f32(va[8 + j], c1h.hf[j], c1l.hf[j]);

        __syncthreads();
        *(int4*)&Ah[2*h  ][lr][0] = c0h.v;
        *(int4*)&Ah[2*h+1][lr][0] = c1h.v;
        *(int4*)&Al[2*h  ][lr][0] = c0l.v;
        *(int4*)&Al[2*h+1][lr][0] = c1l.v;
        *(int4*)&Bh[2*h  ][lr][0] = bh0;
        *(int4*)&Bh[2*h+1][lr][0] = bh1;
        *(int4*)&Bl[2*h  ][lr][0] = bl0;
        *(int4*)&Bl[2*h+1][lr][0] = bl1;
        __syncthreads();

        half8 fah[4], fal[4], fbh[4], fbl[4];
#pragma unroll
        for (int t = 0; t < 4; ++t) {
            fah[t] = *(const half8*)&Ah[quad][mw*64 + t*16 + l15][0];
            fal[t] = *(const half8*)&Al[quad][mw*64 + t*16 + l15][0];
            fbh[t] = *(const half8*)&Bh[quad][nw*64 + t*16 + l15][0];
            fbl[t] = *(const half8*)&Bl[quad][nw*64 + t*16 + l15][0];
        }
#pragma unroll
        for (int ti = 0; ti < 4; ++ti)
#pragma unroll
            for (int tj = 0; tj < 4; ++tj) {
                accA[ti][tj] = __builtin_amdgcn_mfma_f32_16x16x32_f16(fah[ti], fbh[tj], accA[ti][tj], 0, 0, 0);
                accB[ti][tj] = __builtin_amdgcn_mfma_f32_16x16x32_f16(fah[ti], fbl[tj], accB[ti][tj], 0, 0, 0);
                accB[ti][tj] = __builtin_amdgcn_mfma_f32_16x16x32_f16(fal[ti], fbh[tj], accB[ti][tj], 0, 0, 0);
            }
    }

#pragma unroll
    for (int tj = 0; tj < 4; ++tj) {
        const int o = bn*128 + nw*64 + tj*16 + l15;
        const float alpha = ab[o], beta = ab[256 + o];
#pragma unroll
        for (int ti = 0; ti < 4; ++ti) {
            const int m0 = bm*128 + mw*64 + ti*16 + quad*4;
#pragma unroll
            for (int r = 0; r < 4; ++r) {
                float c = accA[ti][tj][r] + accB[ti][tj][r] * (1.0f/2048.0f);
                float z = c * alpha + beta;
                _Float16 zh, zl;
                split_f32(z, zh, zl);
                const int m  = m0 + r;
                const int a2 = m / 63;
                const int t2 = m - a2 * 63;
                const size_t off = ((size_t)a2 * 66 + t2 + 1) * 256 + o;  // padded row t+1
                z1ph[off] = zh;
                z1pl[off] = zl;
            }
        }
    }
}

// ---------------------------------------------------------------------------
// K2: conv2 + bn2 + cuba1 FUSED (R4 proven). M-block = 2 n x 64 t-rows.
// ---------------------------------------------------------------------------
__global__ __launch_bounds__(256, 2) void conv2_cuba_mfma(
    const _Float16* __restrict__ z1ph, const _Float16* __restrict__ z1pl,
    const _Float16* __restrict__ w2h, const _Float16* __restrict__ w2l,
    const float* __restrict__ ab, _Float16* __restrict__ s1)
{
    __shared__ _Float16 SMEM[32768];     // 64 KB: staging during K-loop, z-tile after
    _Float16 (*Ah)[128][8] = reinterpret_cast<_Float16(*)[128][8]>(SMEM);
    _Float16 (*Al)[128][8] = reinterpret_cast<_Float16(*)[128][8]>(SMEM + 8192);
    _Float16 (*Bh)[128][8] = reinterpret_cast<_Float16(*)[128][8]>(SMEM + 16384);
    _Float16 (*Bl)[128][8] = reinterpret_cast<_Float16(*)[128][8]>(SMEM + 24576);

    const int tid = threadIdx.x;
    const int bm = blockIdx.x, bn = blockIdx.y;
    const int lr = tid & 127;
    const int h  = tid >> 7;

    const int n0 = bm * 2;
    const int an = lr >> 6, at = lr & 63;           // m-row = an*64 + at (at=63: pad)
    const _Float16* pAh = z1ph + ((size_t)(n0 + an) * 66 + at) * 256 + h * 8;
    const _Float16* pAl = z1pl + ((size_t)(n0 + an) * 66 + at) * 256 + h * 8;
    const _Float16* pBh = w2h + (size_t)(bn * 128 + lr) * 768 + h * 8;
    const _Float16* pBl = w2l + (size_t)(bn * 128 + lr) * 768 + h * 8;

    const int lane = tid & 63;
    const int wv   = tid >> 6;
    const int mw   = wv & 1, nw = wv >> 1;
    const int quad = lane >> 4;
    const int l15  = lane & 15;

    floatx4 accA[4][4] = {};
    floatx4 accB[4][4] = {};

    for (int it = 0; it < 12; ++it) {
        __syncthreads();                 // previous tile fully consumed
#pragma unroll
        for (int q = 0; q < 4; ++q) {    // slot (kq = q*2+h, row = lr)
            lds_dma16(pAh + q * 16, &Ah[q*2 + h][lr][0]);
            lds_dma16(pAl + q * 16, &Al[q*2 + h][lr][0]);
            lds_dma16(pBh + q * 16, &Bh[q*2 + h][lr][0]);
            lds_dma16(pBl + q * 16, &Bl[q*2 + h][lr][0]);
        }
        __syncthreads();                 // implicit vmcnt(0): DMA landed

#pragma unroll
        for (int ks = 0; ks < 2; ++ks) {
            half8 fah[4], fal[4], fbh[4], fbl[4];
#pragma unroll
            for (int t = 0; t < 4; ++t) {
                fah[t] = *(const half8*)&Ah[ks*4 + quad][mw*64 + t*16 + l15][0];
                fal[t] = *(const half8*)&Al[ks*4 + quad][mw*64 + t*16 + l15][0];
                fbh[t] = *(const half8*)&Bh[ks*4 + quad][nw*64 + t*16 + l15][0];
                fbl[t] = *(const half8*)&Bl[ks*4 + quad][nw*64 + t*16 + l15][0];
            }
#pragma unroll
            for (int ti = 0; ti < 4; ++ti)
#pragma unroll
                for (int tj = 0; tj < 4; ++tj) {
                    accA[ti][tj] = __builtin_amdgcn_mfma_f32_16x16x32_f16(fah[ti], fbh[tj], accA[ti][tj], 0, 0, 0);
                    accB[ti][tj] = __builtin_amdgcn_mfma_f32_16x16x32_f16(fah[ti], fbl[tj], accB[ti][tj], 0, 0, 0);
                    accB[ti][tj] = __builtin_amdgcn_mfma_f32_16x16x32_f16(fal[ti], fbh[tj], accB[ti][tj], 0, 0, 0);
                }
        }
        pAh += 64; pAl += 64; pBh += 64; pBl += 64;
    }

    // ---- fused epilogue: z tile -> LDS fp32 [128 m][128 c], then LIF scan ----
    __syncthreads();                     // all waves done reading staging
    float* zt = (float*)SMEM;            // 128*128 fp32 = 64 KB (exact fit)
#pragma unroll
    for (int tj = 0; tj < 4; ++tj) {
        const int cl = nw*64 + tj*16 + l15;
        const int o  = bn*128 + cl;
        const float alpha = ab[o], beta = ab[256 + o];
#pragma unroll
        for (int ti = 0; ti < 4; ++ti) {
            const int m0 = mw*64 + ti*16 + quad*4;
#pragma unroll
            for (int r = 0; r < 4; ++r) {
                float c = accA[ti][tj][r] + accB[ti][tj][r] * (1.0f/2048.0f);
                zt[(m0 + r) * 128 + cl] = c * alpha + beta;
            }
        }
    }
    __syncthreads();

    // cuba1: thread owns (nl, cloc); reads LDS, writes coalesced fp16 spikes.
    const int nl   = tid >> 7;
    const int cloc = tid & 127;
    const int n    = n0 + nl;
    _Float16* srow = s1 + (size_t)n * 16128 + bn*128 + cloc;
    float cur = 0.f, vol = 0.f;
    for (int t = 0; t < 63; ++t) {
        float xv = zt[(nl*64 + t) * 128 + cloc];
        cur = 0.1f * cur + xv;
        vol = 0.1f * vol + cur;
        bool sp = (vol - 0.3f) >= 0.f;
        srow[(size_t)t * 256] = sp ? (_Float16)1.0f : (_Float16)0.0f;
        if (sp) vol = 0.f;
    }
}

// ---------------------------------------------------------------------------
// K3: dense1 + cuba2 FUSED (R4 proven). Masks -> 1 MB M2g buffer.
// ---------------------------------------------------------------------------
__global__ __launch_bounds__(256, 2) void dense1_mask_mfma(
    const _Float16* __restrict__ s1,
    const _Float16* __restrict__ wdh, const _Float16* __restrict__ wdl,
    unsigned long long* __restrict__ M2g)
{
    __shared__ _Float16 SMEM[32768];
    _Float16 (*As)[128][8] = reinterpret_cast<_Float16(*)[128][8]>(SMEM);
    _Float16 (*Bh)[128][8] = reinterpret_cast<_Float16(*)[128][8]>(SMEM + 8192);
    _Float16 (*Bl)[128][8] = reinterpret_cast<_Float16(*)[128][8]>(SMEM + 16384);

    const int tid = threadIdx.x;
    const int bm = blockIdx.x, bn = blockIdx.y;
    const int lr = tid & 127;
    const int h  = tid >> 7;

    const int n0 = bm * 2;
    const int an = lr >> 6, at = lr & 63;
    const _Float16* pA  = s1  + ((size_t)(n0 + an) * 63 + at) * 256 + h * 8;
    const _Float16* pBh = wdh + (size_t)(bn * 128 + lr) * 256 + h * 8;
    const _Float16* pBl = wdl + (size_t)(bn * 128 + lr) * 256 + h * 8;

    const int lane = tid & 63;
    const int wv   = tid >> 6;
    const int mw   = wv & 1, nw = wv >> 1;
    const int quad = lane >> 4;
    const int l15  = lane & 15;

    floatx4 accA[4][4] = {};
    floatx4 accB[4][4] = {};

    for (int it = 0; it < 4; ++it) {
        __syncthreads();
#pragma unroll
        for (int q = 0; q < 4; ++q) {
            lds_dma16(pA  + q * 16, &As[q*2 + h][lr][0]);
            lds_dma16(pBh + q * 16, &Bh[q*2 + h][lr][0]);
            lds_dma16(pBl + q * 16, &Bl[q*2 + h][lr][0]);
        }
        __syncthreads();

#pragma unroll
        for (int ks = 0; ks < 2; ++ks) {
            half8 fa[4], fbh[4], fbl[4];
#pragma unroll
            for (int t = 0; t < 4; ++t) {
                fa[t]  = *(const half8*)&As[ks*4 + quad][mw*64 + t*16 + l15][0];
                fbh[t] = *(const half8*)&Bh[ks*4 + quad][nw*64 + t*16 + l15][0];
                fbl[t] = *(const half8*)&Bl[ks*4 + quad][nw*64 + t*16 + l15][0];
            }
#pragma unroll
            for (int ti = 0; ti < 4; ++ti)
#pragma unroll
                for (int tj = 0; tj < 4; ++tj) {
                    accA[ti][tj] = __builtin_amdgcn_mfma_f32_16x16x32_f16(fa[ti], fbh[tj], accA[ti][tj], 0, 0, 0);
                    accB[ti][tj] = __builtin_amdgcn_mfma_f32_16x16x32_f16(fa[ti], fbl[tj], accB[ti][tj], 0, 0, 0);
                }
        }
        pA += 64; pBh += 64; pBl += 64;
    }

    // ---- fused epilogue: y tile -> LDS, cuba2 scan -> spike mask ----
    __syncthreads();
    float* yt = (float*)SMEM;
#pragma unroll
    for (int tj = 0; tj < 4; ++tj) {
        const int cl = nw*64 + tj*16 + l15;
#pragma unroll
        for (int ti = 0; ti < 4; ++ti) {
            const int m0 = mw*64 + ti*16 + quad*4;
#pragma unroll
            for (int r = 0; r < 4; ++r)
                yt[(m0 + r) * 128 + cl] =
                    accA[ti][tj][r] + accB[ti][tj][r] * (1.0f/2048.0f);
        }
    }
    __syncthreads();

    const int nl   = tid >> 7;
    const int oloc = tid & 127;
    unsigned long long mask = 0ull;
    float v = 0.f;
    for (int t = 0; t < 63; ++t) {
        float yv = yt[(nl*64 + t) * 128 + oloc];
        v = 0.9f * v + yv;               // cd=0 -> i = x
        if ((v - 0.1f) >= 0.f) { mask |= (1ull << t); v = 0.f; }
    }
    M2g[(size_t)(n0 + nl) * 256 + bn*128 + oloc] = mask;
}

// ---------------------------------------------------------------------------
// K4: tail — dense2 over spike masks + cuba3 -> out.
// ---------------------------------------------------------------------------
__global__ __launch_bounds__(256) void snn_tail(
    const unsigned long long* __restrict__ M2g, const float* __restrict__ w2,
    float* __restrict__ out)
{
    __shared__ unsigned long long M2[256];
    __shared__ float Y[2 * 63];
    const int n   = blockIdx.x;
    const int tid = threadIdx.x;

    M2[tid] = M2g[(size_t)n * 256 + tid];
    __syncthreads();

    if (tid < 126) {
        const int cls = tid / 63;
        const int t   = tid - cls * 63;
        const float* wrow = w2 + cls * 256;
        float acc = 0.f;
#pragma unroll 4
        for (int o = 0; o < 256; ++o)
            acc += ((M2[o] >> t) & 1ull) ? wrow[o] : 0.f;
        Y[cls * 63 + t] = acc;
    }
    __syncthreads();
    if (tid < 2) {
        float v = 0.f;
        float* orow = out + (size_t)n * 126 + tid * 63;
        for (int t = 0; t < 63; ++t) {
            v = 0.9f * v + Y[tid * 63 + t];
            float u = v - 0.1f;
            float s = (u >= 0.f) ? 1.f : 0.f;
            orow[t] = s;
            v = (u >= 0.f) ? 0.f : v;
        }
    }
}

// ---------------------------------------------------------------------------
extern "C" void kernel_launch(void* const* d_in, const int* in_sizes, int n_in,
                              void* d_out, int out_size, void* d_ws, size_t ws_size,
                              hipStream_t stream)
{
    const float* x    = (const float*)d_in[0];
    const float* c1w  = (const float*)d_in[1];
    const float* c1b  = (const float*)d_in[2];
    const float* g1   = (const float*)d_in[3];
    const float* b1   = (const float*)d_in[4];
    const float* m1   = (const float*)d_in[5];
    const float* v1   = (const float*)d_in[6];
    const float* c2w  = (const float*)d_in[7];
    const float* c2b  = (const float*)d_in[8];
    const float* g2   = (const float*)d_in[9];
    const float* b2   = (const float*)d_in[10];
    const float* m2   = (const float*)d_in[11];
    const float* v2   = (const float*)d_in[12];
    const float* w1   = (const float*)d_in[13];
    const float* w2   = (const float*)d_in[14];
    float* out = (float*)d_out;

    float* ws = (float*)d_ws;
    // layout (float units):
    //   [0,        4325376)   z1ph  (padded [512][66][256] fp16)
    //   [4325376,  8650752)   z1pl
    //   [8650752, 12779520)   s1    ([512][63][256] fp16)
    //   [12779520,13041664)   M2g   ([512][256] u64 = 1 MB)
    //   [13041664, ...)       weight limbs + ab
    _Float16* z1ph = (_Float16*)ws;
    _Float16* z1pl = (_Float16*)(ws + 4325376);
    _Float16* s1   = (_Float16*)(ws + 8650752);
    unsigned long long* M2g = (unsigned long long*)(ws + 12779520);
    float*    wsp  = ws + 13041664;
    _Float16* w1h = (_Float16*)wsp;                                 // 262,144 f
    _Float16* w1l = (_Float16*)(wsp + 262144);                      // 262,144 f
    _Float16* w2h = (_Float16*)(wsp + 2*262144);                    //  98,304 f
    _Float16* w2l = (_Float16*)(wsp + 2*262144 + 98304);            //  98,304 f
    _Float16* wdh = (_Float16*)(wsp + 2*262144 + 2*98304);          //  32,768 f
    _Float16* wdl = (_Float16*)(wsp + 2*262144 + 2*98304 + 32768);  //  32,768 f
    float*    ab1 = wsp + 2*262144 + 2*98304 + 2*32768;
    float*    ab2 = ab1 + 512;

    prep_kernel<<<1024, 256, 0, stream>>>(c1w, c1b, g1, b1, m1, v1,
                                          c2w, c2b, g2, b2, m2, v2,
                                          w1, w1h, w1l, w2h, w2l, wdh, wdl,
                                          z1ph, z1pl, ab1, ab2);
    conv1_mfma<<<dim3(252, 2), 256, 0, stream>>>(x, w1h, w1l, ab1, z1ph, z1pl);
    conv2_cuba_mfma<<<dim3(256, 2), 256, 0, stream>>>(z1ph, z1pl, w2h, w2l, ab2, s1);
    dense1_mask_mfma<<<dim3(256, 2), 256, 0, stream>>>(s1, wdh, wdl, M2g);
    snn_tail<<<512, 256, 0, stream>>>(M2g, w2, out);
}